// Round 5
// baseline (442.355 us; speedup 1.0000x reference)
//
#include <hip/hip_runtime.h>
#include <cstddef>

// N=Q=16384, D=3. d_out (flat f32): mask [Q*N] | row_splits [Q+1] | weights [Q*N].
// Weights region starts at abs elem ≡ 1 (mod 4); aligned weights quads cover row
// elems {4k-1..4k+2}. Quad slot 0 comes from the left neighbor: thread-local w,
// shfl_up across lanes, direct recompute at lane 0, whead at row heads.
// R4 post-mortem: store path is issue-limited per VMEM instruction -> everything
// dwordx4. R5: FMA contraction + VEC=8 to cut VALU overhead per pair.

namespace {

constexpr int NPTS = 16384;
constexpr int NQ   = 16384;
constexpr int QB   = 8;     // queries per block
constexpr int TPB  = 256;   // threads per block
constexpr int VEC  = 8;     // consecutive points per thread per iteration
constexpr int ITERS = NPTS / (TPB * VEC); // 8

__device__ __forceinline__ float mulrn(float a, float b) { return __fmul_rn(a, b); }
__device__ __forceinline__ float addrn(float a, float b) { return __fadd_rn(a, b); }

// squared distance, FMA-contracted, clamped at 0
__device__ __forceinline__ float sqdist(float qx, float qy, float qz, float q2,
                                        float dx, float dy, float dz, float d2) {
    const float dot = __fmaf_rn(qx, dx, __fmaf_rn(qy, dy, __fmul_rn(qz, dz)));
    const float s   = __fmaf_rn(-2.0f, dot, __fadd_rn(q2, d2));
    return fmaxf(s, 0.0f);
}

__device__ __forceinline__ float norm2(float x, float y, float z) {
    return __fmaf_rn(x, x, __fmaf_rn(y, y, __fmul_rn(z, z)));
}

__global__ __launch_bounds__(TPB) void ball_kernel(
    const float* __restrict__ data,      // [N,3]
    const float* __restrict__ queries,   // [Q,3]
    const float* __restrict__ radius_p,  // [1]
    float* __restrict__ out,
    int* __restrict__ counts)            // [Q] in workspace
{
    const int tid  = threadIdx.x;
    const int lane = tid & 63;
    const int q0   = blockIdx.x * QB;

    __shared__ float qs[(QB + 1) * 3];   // queries q0-1 .. q0+QB-1
    __shared__ int   scnt[QB];
    if (tid < (QB + 1) * 3) {
        int src = q0 * 3 - 3 + tid;
        if (src < 0) src = 0;            // block 0 dummy; its row-head slot lands on
                                         // row_splits[Q], overwritten by scan after.
        qs[tid] = queries[src];
    }
    if (tid < QB) scnt[tid] = 0;
    __syncthreads();

    const float r  = radius_p[0];
    const float r2 = mulrn(r, r);

    // Last data point (row-head weights slots refer to prev row's last element).
    const float lxx = data[(size_t)(NPTS - 1) * 3 + 0];
    const float lyy = data[(size_t)(NPTS - 1) * 3 + 1];
    const float lzz = data[(size_t)(NPTS - 1) * 3 + 2];
    const float l2  = norm2(lxx, lyy, lzz);

    float qx[QB], qy[QB], qz[QB], q2v[QB], whead[QB];
#pragma unroll
    for (int i = 0; i < QB; ++i) {
        qx[i] = qs[3 * (i + 1) + 0];
        qy[i] = qs[3 * (i + 1) + 1];
        qz[i] = qs[3 * (i + 1) + 2];
        q2v[i] = norm2(qx[i], qy[i], qz[i]);
        // weight of (query q0+i-1, point NPTS-1) -> previous row's last element
        const float px = qs[3 * i + 0], py = qs[3 * i + 1], pz = qs[3 * i + 2];
        const float p2 = norm2(px, py, pz);
        const float sq = sqdist(px, py, pz, p2, lxx, lyy, lzz, l2);
        whead[i] = (sq <= r2) ? sq : 0.0f;
    }

    int cnt[QB];
#pragma unroll
    for (int i = 0; i < QB; ++i) cnt[i] = 0;

    float* __restrict__ mask = out;
    float* __restrict__ wts  = out + ((size_t)NQ * NPTS + NQ + 1);

    for (int it = 0; it < ITERS; ++it) {
        const int nb = (it * TPB + tid) * VEC;
        const float* dbase = data + (size_t)nb * 3;   // 96B-aligned
        const float4 dA = *reinterpret_cast<const float4*>(dbase + 0);
        const float4 dB = *reinterpret_cast<const float4*>(dbase + 4);
        const float4 dC = *reinterpret_cast<const float4*>(dbase + 8);
        const float4 dD = *reinterpret_cast<const float4*>(dbase + 12);
        const float4 dE = *reinterpret_cast<const float4*>(dbase + 16);
        const float4 dF = *reinterpret_cast<const float4*>(dbase + 20);
        const float dx[VEC] = {dA.x, dA.w, dB.z, dC.y, dD.x, dD.w, dE.z, dF.y};
        const float dy[VEC] = {dA.y, dB.x, dB.w, dC.z, dD.y, dE.x, dE.w, dF.z};
        const float dz[VEC] = {dA.z, dB.y, dC.x, dC.w, dD.z, dE.y, dF.x, dF.w};
        float d2[VEC];
#pragma unroll
        for (int j = 0; j < VEC; ++j) d2[j] = norm2(dx[j], dy[j], dz[j]);

        // Left-neighbor point (nb-1), clamped at 0 (nb==0 slot comes from whead).
        const int pm1 = (nb == 0) ? 0 : nb - 1;
        const float mx = data[(size_t)pm1 * 3 + 0];
        const float my = data[(size_t)pm1 * 3 + 1];
        const float mz = data[(size_t)pm1 * 3 + 2];
        const float m2 = norm2(mx, my, mz);

        const bool rowhead = (tid == 0 && it == 0);

#pragma unroll
        for (int q = 0; q < QB; ++q) {
            float m[VEC], w[VEC];
#pragma unroll
            for (int j = 0; j < VEC; ++j) {
                const float sq = sqdist(qx[q], qy[q], qz[q], q2v[q],
                                        dx[j], dy[j], dz[j], d2[j]);
                const bool in = (sq <= r2);
                m[j] = in ? 1.0f : 0.0f;
                w[j] = in ? sq : 0.0f;
                cnt[q] += in ? 1 : 0;
            }
            // Quad slot 0 at row elem nb-1: previous lane's w[7] via shfl;
            // lane 0 recomputes point nb-1 directly (bit-identical formula).
            const float sqm = sqdist(qx[q], qy[q], qz[q], q2v[q], mx, my, mz, m2);
            const float wprev = (sqm <= r2) ? sqm : 0.0f;
            const float wsh = __shfl_up(w[7], 1);
            float slot0 = (lane == 0) ? wprev : wsh;
            if (rowhead) slot0 = whead[q];

            const size_t row = (size_t)(q0 + q) * NPTS;
            *reinterpret_cast<float4*>(mask + row + nb) =
                make_float4(m[0], m[1], m[2], m[3]);
            *reinterpret_cast<float4*>(mask + row + nb + 4) =
                make_float4(m[4], m[5], m[6], m[7]);
            *reinterpret_cast<float4*>(wts + row + nb - 1) =
                make_float4(slot0, w[0], w[1], w[2]);
            *reinterpret_cast<float4*>(wts + row + nb + 3) =
                make_float4(w[3], w[4], w[5], w[6]);
            // w[7] is the next thread's slot0 (or whead / tail special case).
        }
    }

    // Very last weights element (row NQ-1, elem NPTS-1) has no quad owner.
    if (q0 == NQ - QB && tid == TPB - 1) {
        const float sq = sqdist(qx[QB-1], qy[QB-1], qz[QB-1], q2v[QB-1],
                                lxx, lyy, lzz, l2);
        wts[(size_t)(NQ - 1) * NPTS + (NPTS - 1)] = (sq <= r2) ? sq : 0.0f;
    }

    // Block reduction of per-thread counts (wave shfl, then LDS atomics).
#pragma unroll
    for (int q = 0; q < QB; ++q) {
        int v = cnt[q];
        for (int off = 32; off >= 1; off >>= 1) v += __shfl_down(v, off);
        if ((tid & 63) == 0) atomicAdd(&scnt[q], v);
    }
    __syncthreads();
    if (tid < QB) counts[q0 + tid] = scnt[tid];
}

constexpr int STPB  = 256;
constexpr int CHUNK = NQ / STPB; // 64

__global__ __launch_bounds__(STPB) void scan_kernel(
    const int* __restrict__ counts, float* __restrict__ out)
{
    __shared__ int sums[STPB];
    const int tid  = threadIdx.x;
    const int base = tid * CHUNK;

    int s = 0;
    for (int i = 0; i < CHUNK; ++i) s += counts[base + i];
    sums[tid] = s;
    __syncthreads();

    for (int off = 1; off < STPB; off <<= 1) {
        int v = 0;
        if (tid >= off) v = sums[tid - off];
        __syncthreads();
        sums[tid] += v;
        __syncthreads();
    }

    int run = (tid == 0) ? 0 : sums[tid - 1];
    float* rs = out + (size_t)NQ * NPTS;
    if (tid == 0) rs[0] = 0.0f;
    for (int i = 0; i < CHUNK; ++i) {
        run += counts[base + i];
        rs[base + i + 1] = (float)run;
    }
}

} // namespace

extern "C" void kernel_launch(void* const* d_in, const int* in_sizes, int n_in,
                              void* d_out, int out_size, void* d_ws, size_t ws_size,
                              hipStream_t stream) {
    const float* data    = (const float*)d_in[0];
    const float* queries = (const float*)d_in[1];
    const float* radius  = (const float*)d_in[2];
    float* out  = (float*)d_out;
    int* counts = (int*)d_ws;

    hipLaunchKernelGGL(ball_kernel, dim3(NQ / QB), dim3(TPB), 0, stream,
                       data, queries, radius, out, counts);
    hipLaunchKernelGGL(scan_kernel, dim3(1), dim3(STPB), 0, stream, counts, out);
}

// Round 6
// 409.601 us; speedup vs baseline: 1.0800x; 1.0800x over previous
//
#include <hip/hip_runtime.h>
#include <cstddef>

// N=Q=16384, D=3. d_out (flat f32): mask [Q*N] | row_splits [Q+1] | weights [Q*N].
// Weights region starts at abs elem ≡ 1 (mod 4); aligned weights quads cover row
// elems {4k-1..4k+2}. Quad slot 0 = left neighbor's value: shfl_up across lanes,
// direct recompute at lane 0, prev-row tail at row heads.
// R4: store path wants max bytes/instr -> all dwordx4.  R5: VALU cuts neutral.
// R6: q-loop OUTERMOST -> 2 live write streams per block (fill-like), scalar
// per-q state (low VGPR); points re-read per q are L2-resident (~free).

namespace {

constexpr int NPTS = 16384;
constexpr int NQ   = 16384;
constexpr int QB   = 8;     // queries (rows) per block
constexpr int TPB  = 256;   // threads per block
constexpr int VEC  = 8;     // consecutive points per thread per iteration
constexpr int ITERS = NPTS / (TPB * VEC); // 8

__device__ __forceinline__ float norm2(float x, float y, float z) {
    return __fmaf_rn(x, x, __fmaf_rn(y, y, __fmul_rn(z, z)));
}

// squared distance, FMA-contracted, clamped at 0 (matches R5 numerics)
__device__ __forceinline__ float sqdist(float qx, float qy, float qz, float q2,
                                        float dx, float dy, float dz, float d2) {
    const float dot = __fmaf_rn(qx, dx, __fmaf_rn(qy, dy, __fmul_rn(qz, dz)));
    const float s   = __fmaf_rn(-2.0f, dot, __fadd_rn(q2, d2));
    return fmaxf(s, 0.0f);
}

__global__ __launch_bounds__(TPB) void ball_kernel(
    const float* __restrict__ data,      // [N,3]
    const float* __restrict__ queries,   // [Q,3]
    const float* __restrict__ radius_p,  // [1]
    float* __restrict__ out,
    int* __restrict__ counts)            // [Q] in workspace
{
    const int tid  = threadIdx.x;
    const int lane = tid & 63;
    const int q0   = blockIdx.x * QB;

    __shared__ float qs[(QB + 1) * 3];   // queries q0-1 .. q0+QB-1
    __shared__ int   scnt[QB];
    if (tid < (QB + 1) * 3) {
        int src = q0 * 3 - 3 + tid;
        if (src < 0) src = 0;            // block 0 dummy; its row-head slot lands on
                                         // row_splits[Q], overwritten by scan after.
        qs[tid] = queries[src];
    }
    if (tid < QB) scnt[tid] = 0;
    __syncthreads();

    const float r  = radius_p[0];
    const float r2 = __fmul_rn(r, r);

    // Last data point (row-head weights slots refer to prev row's last element).
    const float lxx = data[(size_t)(NPTS - 1) * 3 + 0];
    const float lyy = data[(size_t)(NPTS - 1) * 3 + 1];
    const float lzz = data[(size_t)(NPTS - 1) * 3 + 2];
    const float l2  = norm2(lxx, lyy, lzz);

    float* __restrict__ mask = out;
    float* __restrict__ wts  = out + ((size_t)NQ * NPTS + NQ + 1);

#pragma unroll 1
    for (int q = 0; q < QB; ++q) {
        const float qxq = qs[3 * (q + 1) + 0];
        const float qyq = qs[3 * (q + 1) + 1];
        const float qzq = qs[3 * (q + 1) + 2];
        const float q2q = norm2(qxq, qyq, qzq);

        // Row-head slot value: weight(query q0+q-1, point NPTS-1).
        const float px = qs[3 * q + 0], py = qs[3 * q + 1], pz = qs[3 * q + 2];
        const float sqh = sqdist(px, py, pz, norm2(px, py, pz), lxx, lyy, lzz, l2);
        const float wheadq = (sqh <= r2) ? sqh : 0.0f;

        float* __restrict__ mrow = mask + (size_t)(q0 + q) * NPTS;
        float* __restrict__ wrow = wts  + (size_t)(q0 + q) * NPTS;

        int cnt = 0;

#pragma unroll 1
        for (int it = 0; it < ITERS; ++it) {
            const int nb = (it * TPB + tid) * VEC;
            const float* dbase = data + (size_t)nb * 3;   // 96B-aligned
            const float4 dA = *reinterpret_cast<const float4*>(dbase + 0);
            const float4 dB = *reinterpret_cast<const float4*>(dbase + 4);
            const float4 dC = *reinterpret_cast<const float4*>(dbase + 8);
            const float4 dD = *reinterpret_cast<const float4*>(dbase + 12);
            const float4 dE = *reinterpret_cast<const float4*>(dbase + 16);
            const float4 dF = *reinterpret_cast<const float4*>(dbase + 20);

            // Left-neighbor point (nb-1), clamped at 0 (nb==0 slot uses wheadq).
            const int pm1 = (nb == 0) ? 0 : nb - 1;
            const float mx = data[(size_t)pm1 * 3 + 0];
            const float my = data[(size_t)pm1 * 3 + 1];
            const float mz = data[(size_t)pm1 * 3 + 2];

            const float dx[VEC] = {dA.x, dA.w, dB.z, dC.y, dD.x, dD.w, dE.z, dF.y};
            const float dy[VEC] = {dA.y, dB.x, dB.w, dC.z, dD.y, dE.x, dE.w, dF.z};
            const float dz[VEC] = {dA.z, dB.y, dC.x, dC.w, dD.z, dE.y, dF.x, dF.w};

            float m[VEC], w[VEC];
#pragma unroll
            for (int j = 0; j < VEC; ++j) {
                const float d2 = norm2(dx[j], dy[j], dz[j]);
                const float sq = sqdist(qxq, qyq, qzq, q2q, dx[j], dy[j], dz[j], d2);
                const bool in = (sq <= r2);
                m[j] = in ? 1.0f : 0.0f;
                w[j] = in ? sq : 0.0f;
                cnt += in ? 1 : 0;
            }

            // Quad slot 0 at row elem nb-1: previous lane's w[7] via shfl;
            // lane 0 recomputes point nb-1 directly (bit-identical formula).
            const float m2  = norm2(mx, my, mz);
            const float sqm = sqdist(qxq, qyq, qzq, q2q, mx, my, mz, m2);
            const float wprev = (sqm <= r2) ? sqm : 0.0f;
            const float wsh = __shfl_up(w[7], 1);
            float slot0 = (lane == 0) ? wprev : wsh;
            if (tid == 0 && it == 0) slot0 = wheadq;

            *reinterpret_cast<float4*>(mrow + nb) =
                make_float4(m[0], m[1], m[2], m[3]);
            *reinterpret_cast<float4*>(mrow + nb + 4) =
                make_float4(m[4], m[5], m[6], m[7]);
            *reinterpret_cast<float4*>(wrow + nb - 1) =
                make_float4(slot0, w[0], w[1], w[2]);
            *reinterpret_cast<float4*>(wrow + nb + 3) =
                make_float4(w[3], w[4], w[5], w[6]);
            // w[7] is the next thread's slot0 (or row-head / global-tail case).
        }

        // Reduce this row's count across the block.
        for (int off = 32; off >= 1; off >>= 1) cnt += __shfl_down(cnt, off);
        if (lane == 0) atomicAdd(&scnt[q], cnt);
    }

    // Very last weights element (row NQ-1, elem NPTS-1) has no quad owner.
    if (q0 == NQ - QB && tid == TPB - 1) {
        const float qxq = qs[3 * QB + 0];
        const float qyq = qs[3 * QB + 1];
        const float qzq = qs[3 * QB + 2];
        const float sq = sqdist(qxq, qyq, qzq, norm2(qxq, qyq, qzq),
                                lxx, lyy, lzz, l2);
        wts[(size_t)(NQ - 1) * NPTS + (NPTS - 1)] = (sq <= r2) ? sq : 0.0f;
    }

    __syncthreads();
    if (tid < QB) counts[q0 + tid] = scnt[tid];
}

constexpr int STPB  = 256;
constexpr int CHUNK = NQ / STPB; // 64

__global__ __launch_bounds__(STPB) void scan_kernel(
    const int* __restrict__ counts, float* __restrict__ out)
{
    __shared__ int sums[STPB];
    const int tid  = threadIdx.x;
    const int base = tid * CHUNK;

    int s = 0;
    for (int i = 0; i < CHUNK; ++i) s += counts[base + i];
    sums[tid] = s;
    __syncthreads();

    for (int off = 1; off < STPB; off <<= 1) {
        int v = 0;
        if (tid >= off) v = sums[tid - off];
        __syncthreads();
        sums[tid] += v;
        __syncthreads();
    }

    int run = (tid == 0) ? 0 : sums[tid - 1];
    float* rs = out + (size_t)NQ * NPTS;
    if (tid == 0) rs[0] = 0.0f;
    for (int i = 0; i < CHUNK; ++i) {
        run += counts[base + i];
        rs[base + i + 1] = (float)run;
    }
}

} // namespace

extern "C" void kernel_launch(void* const* d_in, const int* in_sizes, int n_in,
                              void* d_out, int out_size, void* d_ws, size_t ws_size,
                              hipStream_t stream) {
    const float* data    = (const float*)d_in[0];
    const float* queries = (const float*)d_in[1];
    const float* radius  = (const float*)d_in[2];
    float* out  = (float*)d_out;
    int* counts = (int*)d_ws;

    hipLaunchKernelGGL(ball_kernel, dim3(NQ / QB), dim3(TPB), 0, stream,
                       data, queries, radius, out, counts);
    hipLaunchKernelGGL(scan_kernel, dim3(1), dim3(STPB), 0, stream, counts, out);
}